// Round 13
// baseline (4725.824 us; speedup 1.0000x reference)
//
#include <hip/hip_runtime.h>
#include <hip/hip_bf16.h>

#define B_ 8
#define N_ 8192
#define C_ 64
#define M_ 2048
#define K_ 32
#define OUT_ 128
#define CIN_ 67
#define HID_ 268
#define EPS_ 1e-6f

typedef short short8 __attribute__((ext_vector_type(8)));
typedef float floatx4 __attribute__((ext_vector_type(4)));

__device__ __forceinline__ unsigned short f2bf(float f) {
  unsigned u = __builtin_bit_cast(unsigned, f);
  u += 0x7fffu + ((u >> 16) & 1u);   // RNE (MFMA input casts only)
  return (unsigned short)(u >> 16);
}
__device__ __forceinline__ float bf2f(unsigned short h) {
  return __builtin_bit_cast(float, (unsigned)h << 16);
}

// XLA-CPU-style fused distance: square fused into the 3-element reduce as FMA,
// index-ascending: d2 = fma(dz,dz, fma(dy,dy, dx*dx)).  (fma(dx,dx,0) == dx*dx)
// This is a 1-ulp-class perturbation vs numpy-seq — exactly what decides a
// sub-ulp near-tie argmax flip (the r10/r11 1.3535 signature).
__device__ __forceinline__ float d2fma(float ax, float ay, float az,
                                       float bx, float by, float bz) {
#pragma clang fp contract(off)
  float dx = ax - bx, dy = ay - by, dz = az - bz;
  return __builtin_fmaf(dz, dz, __builtin_fmaf(dy, dy, dx * dx));
}

__device__ __forceinline__ float gelu_tanh(float v) {
  const float k0 = 0.7978845608028654f;  // sqrt(2/pi)
  const float k1 = 0.044715f;
  float u = k0 * (v + k1 * v * v * v);
  return 0.5f * v * (1.0f + tanhf(u));
}

// ---------------- FPS: one block per batch, 512 threads, 16 pts/thread ----
__global__ __launch_bounds__(512) void fps_kernel(
    const float* __restrict__ x, const int* __restrict__ first_idx,
    float* __restrict__ centers) {   // = d_out[0 .. B*M*3), FLOAT32
  const int b = blockIdx.x;
  const int t = threadIdx.x;
  const float* xb = x + (size_t)b * N_ * 3;

  float px[16], py[16], pz[16], d[16];
#pragma unroll
  for (int i = 0; i < 16; ++i) {
    int p = t + i * 512;
    px[i] = xb[p * 3 + 0];
    py[i] = xb[p * 3 + 1];
    pz[i] = xb[p * 3 + 2];
  }
  __shared__ float s_wv[8];
  __shared__ int s_wi[8];
  __shared__ float s_c[3];

  int fi = first_idx[b];
  float cx = xb[fi * 3 + 0], cy = xb[fi * 3 + 1], cz = xb[fi * 3 + 2];
  if (t == 0) {
    size_t co = (size_t)b * M_ * 3;
    centers[co + 0] = cx; centers[co + 1] = cy; centers[co + 2] = cz;
  }
#pragma unroll
  for (int i = 0; i < 16; ++i) d[i] = d2fma(px[i], py[i], pz[i], cx, cy, cz);

  for (int it = 1; it < M_; ++it) {
    float bv = -1.0f; int bi = 0;
#pragma unroll
    for (int i = 0; i < 16; ++i) {
      if (d[i] > bv) { bv = d[i]; bi = t + i * 512; }   // ascending idx -> first-max kept
    }
#pragma unroll
    for (int off = 1; off < 64; off <<= 1) {
      float ov = __shfl_xor(bv, off);
      int oi = __shfl_xor(bi, off);
      if (ov > bv || (ov == bv && oi < bi)) { bv = ov; bi = oi; }
    }
    if ((t & 63) == 0) { s_wv[t >> 6] = bv; s_wi[t >> 6] = bi; }
    __syncthreads();
    float gv = s_wv[0]; int gi = s_wi[0];
#pragma unroll
    for (int ww = 1; ww < 8; ++ww) {
      float ov = s_wv[ww]; int oi = s_wi[ww];
      if (ov > gv || (ov == gv && oi < gi)) { gv = ov; gi = oi; }
    }
    if (t == (gi & 511)) {   // owner thread broadcasts coords + writes output
      int ii = gi >> 9;
      float ox = 0.f, oy = 0.f, oz = 0.f;
#pragma unroll
      for (int i = 0; i < 16; ++i) if (i == ii) { ox = px[i]; oy = py[i]; oz = pz[i]; }
      s_c[0] = ox; s_c[1] = oy; s_c[2] = oz;
      size_t co = ((size_t)b * M_ + it) * 3;
      centers[co + 0] = ox; centers[co + 1] = oy; centers[co + 2] = oz;
    }
    __syncthreads();
    float ncx = s_c[0], ncy = s_c[1], ncz = s_c[2];
#pragma unroll
    for (int i = 0; i < 16; ++i) {
      float dd = d2fma(px[i], py[i], pz[i], ncx, ncy, ncz);
      d[i] = fminf(d[i], dd);
    }
  }
}

// ---------------- Ball query: one wave per center -------------------------
#define CAP_ 512
__global__ __launch_bounds__(256) void ballq_kernel(
    const float* __restrict__ x, const float* __restrict__ centers,
    int* __restrict__ nbr) {
  __shared__ float cd[4][CAP_];
  __shared__ int cidx[4][CAP_];
  const int w = threadIdx.x >> 6;
  const int lane = threadIdx.x & 63;
  const int cm = blockIdx.x * 4 + w;
  const int b = cm >> 11;  // / M_
  const float* xb = x + (size_t)b * N_ * 3;
  const float ccx = centers[(size_t)cm * 3 + 0];
  const float ccy = centers[(size_t)cm * 3 + 1];
  const float ccz = centers[(size_t)cm * 3 + 2];
  int count = 0;
  for (int base = 0; base < N_; base += 64) {
    int p = base + lane;
    float d2 = d2fma(xb[p * 3 + 0], xb[p * 3 + 1], xb[p * 3 + 2], ccx, ccy, ccz);
    bool isin = d2 < 0.09f;   // f32(0.3**2), strict <
    unsigned long long m = __ballot(isin);
    if (isin) {
      int pos = count + (int)__popcll(m & ((1ull << lane) - 1ull));
      if (pos < CAP_) { cd[w][pos] = d2; cidx[w][pos] = p; }  // index-ordered = stable
    }
    count += (int)__popcll(m);
  }
  if (count > CAP_) count = CAP_;
  int nw = count < K_ ? count : K_;
  for (int cc = lane; cc < count; cc += 64) {
    float dcc = cd[w][cc];
    int rank = 0;
    for (int j = 0; j < count; ++j) {
      float dj = cd[w][j];
      rank += (dj < dcc || (dj == dcc && j < cc)) ? 1 : 0;  // stable order
    }
    if (rank < K_) nbr[(size_t)cm * K_ + rank] = cidx[w][cc];
  }
  // pad: reference's -1 wraps to N-1 on gather
  for (int s = nw + lane; s < K_; s += 64) nbr[(size_t)cm * K_ + s] = N_ - 1;
}

// ---------------- Pack f32 weights into MFMA B-fragment order (bf16) ------
// B-frag for 16x16x32: lane holds B[k = (lane>>4)*8 + j][n = lane&15].
__global__ __launch_bounds__(256) void pack_kernel(
    const float* __restrict__ w1, const float* __restrict__ w2,
    unsigned short* __restrict__ w1p, unsigned short* __restrict__ w2p) {
  int e = blockIdx.x * 256 + threadIdx.x;
  if (e < 3 * 17 * 64 * 8) {
    int j = e & 7, lane = (e >> 3) & 63, fi = e >> 9;
    int kt = fi / 17, nt = fi - kt * 17;
    int k = kt * 32 + (lane >> 4) * 8 + j;
    int n = nt * 16 + (lane & 15);
    float v = (k < CIN_ && n < HID_) ? w1[k * HID_ + n] : 0.f;
    w1p[e] = f2bf(v);
  } else {
    int e2 = e - 3 * 17 * 64 * 8;
    if (e2 < 9 * 8 * 64 * 8) {
      int j = e2 & 7, lane = (e2 >> 3) & 63, fi = e2 >> 9;
      int kt = fi >> 3, nt = fi & 7;
      int k = kt * 32 + (lane >> 4) * 8 + j;
      int n = nt * 16 + (lane & 15);
      float v = (k < HID_) ? w2[k * OUT_ + n] : 0.f;
      w2p[e2] = f2bf(v);
    }
  }
}

// ---------------- Fused gather + MLP + LN + max, one center at a time -----
__global__ __launch_bounds__(512) void mlp_kernel(
    const float* __restrict__ x, const float* __restrict__ features,
    const float* __restrict__ centers, const int* __restrict__ nbr,
    const unsigned short* __restrict__ w1p, const float* __restrict__ b1,
    const float* __restrict__ g1, const float* __restrict__ be1,
    const unsigned short* __restrict__ w2p, const float* __restrict__ b2,
    const float* __restrict__ g2, const float* __restrict__ be2,
    float* __restrict__ out1) {
  __shared__ __align__(16) unsigned short A1[32 * 104];  // comb bf16, K1pad=96 (+8 pad)
  __shared__ __align__(16) unsigned short H1[32 * 296];  // h1 bf16, K2pad=288 (+8 pad)
  __shared__ float H2[32 * 132];                          // h2 f32 (pre-LN2), +4 pad
  __shared__ float s_sum[32], s_sum2[32], s_mu[32], s_rs[32];
  __shared__ int s_nbr[32];
  __shared__ float s_ctr[3];

  const int tid = threadIdx.x;
  const int lane = tid & 63;
  const int wv = tid >> 6;   // wave 0..7
  const int q4 = lane >> 4;  // quad 0..3
  const int nl = lane & 15;

  for (int e = tid; e < 32 * 104; e += 512) A1[e] = 0;
  for (int e = tid; e < 32 * 296; e += 512) H1[e] = 0;
  __syncthreads();

  for (int cm = blockIdx.x; cm < B_ * M_; cm += gridDim.x) {
    const int b = cm >> 11;
    if (tid < 32) s_nbr[tid] = nbr[(size_t)cm * K_ + tid];
    else if (tid < 64) s_sum[tid - 32] = 0.f;
    else if (tid < 96) s_sum2[tid - 64] = 0.f;
    else if (tid < 99) s_ctr[tid - 96] = centers[(size_t)cm * 3 + (tid - 96)];
    __syncthreads();

    // gather: 16 threads per neighbor row
    {
      int r = tid >> 4, j = tid & 15;
      int idx = s_nbr[r];
      const float4* frow = (const float4*)(features + ((size_t)b * N_ + idx) * C_);
      float4 f4 = frow[j];
      int base = r * 104 + j * 4;
      A1[base + 0] = f2bf(f4.x); A1[base + 1] = f2bf(f4.y);
      A1[base + 2] = f2bf(f4.z); A1[base + 3] = f2bf(f4.w);
      if (j == 0) {
        const float* xp = x + ((size_t)b * N_ + idx) * 3;
        A1[r * 104 + 64] = f2bf(xp[0] - s_ctr[0]);
        A1[r * 104 + 65] = f2bf(xp[1] - s_ctr[1]);
        A1[r * 104 + 66] = f2bf(xp[2] - s_ctr[2]);
      }
    }
    __syncthreads();

    // GEMM1: (32x96) @ (96x272), B-frags register-cached from global
    for (int nt = wv; nt < 17; nt += 8) {
      short8 bfr[3];
#pragma unroll
      for (int kt = 0; kt < 3; ++kt)
        bfr[kt] = *(const short8*)(w1p + (size_t)((kt * 17 + nt) * 64 + lane) * 8);
      int col = nt * 16 + nl;
      bool cok = col < HID_;
      float bias = cok ? b1[col] : 0.f;
#pragma unroll
      for (int mt = 0; mt < 2; ++mt) {
        floatx4 acc = {0.f, 0.f, 0.f, 0.f};
        const unsigned short* ap = A1 + (mt * 16 + nl) * 104 + q4 * 8;
#pragma unroll
        for (int kt = 0; kt < 3; ++kt) {
          short8 a = *(const short8*)(ap + kt * 32);
          acc = __builtin_amdgcn_mfma_f32_16x16x32_bf16(a, bfr[kt], acc, 0, 0, 0);
        }
#pragma unroll
        for (int r = 0; r < 4; ++r) {
          int row = mt * 16 + q4 * 4 + r;
          float g = 0.f;
          if (cok) {
            float v = acc[r] + bias;
            g = gelu_tanh(v);
            H1[row * 296 + col] = f2bf(g);
          }
          float s1 = g, s2 = g * g;
#pragma unroll
          for (int off = 1; off < 16; off <<= 1) {
            s1 += __shfl_xor(s1, off);
            s2 += __shfl_xor(s2, off);
          }
          if (nl == 0) { atomicAdd(&s_sum[row], s1); atomicAdd(&s_sum2[row], s2); }
        }
      }
    }
    __syncthreads();
    if (tid < 32) {
      float mu = s_sum[tid] * (1.f / HID_);
      float var = s_sum2[tid] * (1.f / HID_) - mu * mu;
      s_mu[tid] = mu;
      s_rs[tid] = rsqrtf(var + EPS_);
    }
    __syncthreads();
    // LN1 in place (bf16), zero stats for LN2
    for (int e = tid; e < K_ * HID_; e += 512) {
      int r = e / HID_, c = e - r * HID_;
      float g = bf2f(H1[r * 296 + c]);
      float v = (g - s_mu[r]) * s_rs[r] * g1[c] + be1[c];
      H1[r * 296 + c] = f2bf(v);
    }
    if (tid < 32) { s_sum[tid] = 0.f; s_sum2[tid] = 0.f; }
    __syncthreads();

    // GEMM2: (32x288) @ (288x128), one n-tile per wave
    {
      int nt = wv;
      short8 bfr2[9];
#pragma unroll
      for (int kt = 0; kt < 9; ++kt)
        bfr2[kt] = *(const short8*)(w2p + (size_t)((kt * 8 + nt) * 64 + lane) * 8);
      int col = nt * 16 + nl;
      float bias = b2[col];
#pragma unroll
      for (int mt = 0; mt < 2; ++mt) {
        floatx4 acc = {0.f, 0.f, 0.f, 0.f};
        const unsigned short* ap = H1 + (mt * 16 + nl) * 296 + q4 * 8;
#pragma unroll
        for (int kt = 0; kt < 9; ++kt) {
          short8 a = *(const short8*)(ap + kt * 32);
          acc = __builtin_amdgcn_mfma_f32_16x16x32_bf16(a, bfr2[kt], acc, 0, 0, 0);
        }
#pragma unroll
        for (int r = 0; r < 4; ++r) {
          int row = mt * 16 + q4 * 4 + r;
          float v = acc[r] + bias;
          H2[row * 132 + col] = v;
          float s1 = v, s2 = v * v;
#pragma unroll
          for (int off = 1; off < 16; off <<= 1) {
            s1 += __shfl_xor(s1, off);
            s2 += __shfl_xor(s2, off);
          }
          if (nl == 0) { atomicAdd(&s_sum[row], s1); atomicAdd(&s_sum2[row], s2); }
        }
      }
    }
    __syncthreads();
    if (tid < 32) {
      float mu = s_sum[tid] * (1.f / OUT_);
      float var = s_sum2[tid] * (1.f / OUT_) - mu * mu;
      s_mu[tid] = mu;
      s_rs[tid] = rsqrtf(var + EPS_);
    }
    __syncthreads();
    if (tid < OUT_) {
      int col = tid;
      float gg = g2[col], bb = be2[col];
      float mx = -3.4e38f;
#pragma unroll 4
      for (int r = 0; r < K_; ++r) {
        float v = H2[r * 132 + col];
        float o = (v - s_mu[r]) * s_rs[r] * gg + bb;
        mx = fmaxf(mx, o);
      }
      out1[(size_t)cm * OUT_ + col] = mx;   // FLOAT32 output
    }
    __syncthreads();
  }
}

extern "C" void kernel_launch(void* const* d_in, const int* in_sizes, int n_in,
                              void* d_out, int out_size, void* d_ws, size_t ws_size,
                              hipStream_t stream) {
  const float* x = (const float*)d_in[0];
  const float* features = (const float*)d_in[1];
  const int* first_idx = (const int*)d_in[2];
  const float* w1 = (const float*)d_in[3];
  const float* b1 = (const float*)d_in[4];
  const float* g1 = (const float*)d_in[5];
  const float* be1 = (const float*)d_in[6];
  const float* w2 = (const float*)d_in[7];
  const float* b2 = (const float*)d_in[8];
  const float* g2 = (const float*)d_in[9];
  const float* be2 = (const float*)d_in[10];

  // d_out is FLOAT32: centers (8,2048,3) then out (8,2048,128), concatenated.
  float* centers = (float*)d_out;
  float* out1 = (float*)d_out + (size_t)B_ * M_ * 3;

  // ws layout (bytes): nbr [0,2097152) | w1p [2097152,2149376) | w2p [2149376,2223104)
  int* nbr = (int*)d_ws;
  unsigned short* w1p = (unsigned short*)((char*)d_ws + 2097152);
  unsigned short* w2p = (unsigned short*)((char*)d_ws + 2149376);

  pack_kernel<<<dim3(246), dim3(256), 0, stream>>>(w1, w2, w1p, w2p);
  fps_kernel<<<dim3(B_), dim3(512), 0, stream>>>(x, first_idx, centers);
  ballq_kernel<<<dim3((B_ * M_) / 4), dim3(256), 0, stream>>>(x, centers, nbr);
  mlp_kernel<<<dim3(512), dim3(512), 0, stream>>>(x, features, centers, nbr,
                                                  w1p, b1, g1, be1, w2p, b2, g2, be2, out1);
}

// Round 14
// 3270.800 us; speedup vs baseline: 1.4449x; 1.4449x over previous
//
#include <hip/hip_runtime.h>
#include <hip/hip_bf16.h>
#include <math.h>

#define B_ 8
#define N_ 8192
#define C_ 64
#define M_ 2048
#define K_ 32
#define OUT_ 128
#define CIN_ 67
#define HID_ 268
#define EPS_ 1e-6f

typedef short short8 __attribute__((ext_vector_type(8)));
typedef float floatx4 __attribute__((ext_vector_type(4)));

__device__ __forceinline__ unsigned short f2bf(float f) {
  unsigned u = __builtin_bit_cast(unsigned, f);
  u += 0x7fffu + ((u >> 16) & 1u);   // RNE (MFMA input casts only)
  return (unsigned short)(u >> 16);
}
__device__ __forceinline__ float bf2f(unsigned short h) {
  return __builtin_bit_cast(float, (unsigned)h << 16);
}

// Reference-matching distance (verified r13, bit-exact): square fused into the
// 3-element reduce as FMA, index-ascending.
__device__ __forceinline__ float d2fma(float ax, float ay, float az,
                                       float bx, float by, float bz) {
#pragma clang fp contract(off)
  float dx = ax - bx, dy = ay - by, dz = az - bz;
  return __builtin_fmaf(dz, dz, __builtin_fmaf(dy, dy, dx * dx));
}

__device__ __forceinline__ float gelu_tanh(float v) {
  const float k0 = 0.7978845608028654f;  // sqrt(2/pi)
  const float k1 = 0.044715f;
  float u = k0 * (v + k1 * v * v * v);
  return 0.5f * v * (1.0f + tanhf(u));
}

// ---------------- FPS: one block per batch, 512 threads, 16 pts/thread ----
// One barrier per iteration (was two): u64 (d2,idx) keys, double-buffered
// per-wave partials, redundant block-reduce on every thread, winner coords
// re-fetched from global x via wave-uniform L1-hot load (no owner publish).
// Semantics bit-identical to the r13-verified chain: same d2fma, same fminf,
// strict-max with first-index tie-break (u64 key = bits(d)<<32 | ~idx).
__global__ __launch_bounds__(512) void fps_kernel(
    const float* __restrict__ x, const int* __restrict__ first_idx,
    float* __restrict__ centers) {   // = d_out[0 .. B*M*3), FLOAT32
  const int b = blockIdx.x;
  const int t = threadIdx.x;
  const int lane = t & 63;
  const int wv = t >> 6;
  const float* xb = x + (size_t)b * N_ * 3;

  float px[16], py[16], pz[16], d[16];
#pragma unroll
  for (int i = 0; i < 16; ++i) {
    int p = t + i * 512;
    px[i] = xb[p * 3 + 0];
    py[i] = xb[p * 3 + 1];
    pz[i] = xb[p * 3 + 2];
    d[i] = INFINITY;   // fminf(inf, v) == v exactly -> first update installs d0
  }
  __shared__ unsigned long long s_part[2][8];

  int fi = first_idx[b];
  float ncx = xb[fi * 3 + 0], ncy = xb[fi * 3 + 1], ncz = xb[fi * 3 + 2];
  if (t == 0) {
    size_t co = (size_t)b * M_ * 3;
    centers[co + 0] = ncx; centers[co + 1] = ncy; centers[co + 2] = ncz;
  }

  for (int it = 1; it < M_; ++it) {
    // fused: update d with center[it-1], track per-thread argmax (first-max)
    float bv = -1.0f; int bi = 0;
#pragma unroll
    for (int i = 0; i < 16; ++i) {
      float dd = d2fma(px[i], py[i], pz[i], ncx, ncy, ncz);
      float dm = fminf(d[i], dd);
      d[i] = dm;
      if (dm > bv) { bv = dm; bi = t + i * 512; }   // ascending idx scan
    }
    // pack: d>=0 so f32 bits are monotone; ~idx makes ties pick smallest idx
    unsigned long long k =
        ((unsigned long long)__builtin_bit_cast(unsigned, bv) << 32) |
        (unsigned long long)(0xFFFFFFFFu - (unsigned)bi);
#pragma unroll
    for (int off = 1; off < 64; off <<= 1) {
      unsigned long long o = __shfl_xor(k, off);
      k = k > o ? k : o;
    }
    if (lane == 0) s_part[it & 1][wv] = k;
    __syncthreads();
    unsigned long long kk = s_part[it & 1][0];
#pragma unroll
    for (int ww = 1; ww < 8; ++ww) {
      unsigned long long o = s_part[it & 1][ww];
      kk = kk > o ? kk : o;
    }
    int gi = (int)(0xFFFFFFFFu - (unsigned)(kk & 0xFFFFFFFFull));
    int gs = __builtin_amdgcn_readfirstlane(gi);   // uniform -> scalar loads
    ncx = xb[gs * 3 + 0]; ncy = xb[gs * 3 + 1]; ncz = xb[gs * 3 + 2];
    if (t == 0) {
      size_t co = ((size_t)b * M_ + it) * 3;
      centers[co + 0] = ncx; centers[co + 1] = ncy; centers[co + 2] = ncz;
    }
    // no second barrier: next iteration writes the other parity buffer
  }
}

// ---------------- Ball query: one wave per center -------------------------
#define CAP_ 512
__global__ __launch_bounds__(256) void ballq_kernel(
    const float* __restrict__ x, const float* __restrict__ centers,
    int* __restrict__ nbr) {
  __shared__ float cd[4][CAP_];
  __shared__ int cidx[4][CAP_];
  const int w = threadIdx.x >> 6;
  const int lane = threadIdx.x & 63;
  const int cm = blockIdx.x * 4 + w;
  const int b = cm >> 11;  // / M_
  const float* xb = x + (size_t)b * N_ * 3;
  const float ccx = centers[(size_t)cm * 3 + 0];
  const float ccy = centers[(size_t)cm * 3 + 1];
  const float ccz = centers[(size_t)cm * 3 + 2];
  int count = 0;
  for (int base = 0; base < N_; base += 64) {
    int p = base + lane;
    float d2 = d2fma(xb[p * 3 + 0], xb[p * 3 + 1], xb[p * 3 + 2], ccx, ccy, ccz);
    bool isin = d2 < 0.09f;   // f32(0.3**2), strict <
    unsigned long long m = __ballot(isin);
    if (isin) {
      int pos = count + (int)__popcll(m & ((1ull << lane) - 1ull));
      if (pos < CAP_) { cd[w][pos] = d2; cidx[w][pos] = p; }  // index-ordered = stable
    }
    count += (int)__popcll(m);
  }
  if (count > CAP_) count = CAP_;
  int nw = count < K_ ? count : K_;
  for (int cc = lane; cc < count; cc += 64) {
    float dcc = cd[w][cc];
    int rank = 0;
    for (int j = 0; j < count; ++j) {
      float dj = cd[w][j];
      rank += (dj < dcc || (dj == dcc && j < cc)) ? 1 : 0;  // stable order
    }
    if (rank < K_) nbr[(size_t)cm * K_ + rank] = cidx[w][cc];
  }
  // pad: reference's -1 wraps to N-1 on gather
  for (int s = nw + lane; s < K_; s += 64) nbr[(size_t)cm * K_ + s] = N_ - 1;
}

// ---------------- Pack f32 weights into MFMA B-fragment order (bf16) ------
// B-frag for 16x16x32: lane holds B[k = (lane>>4)*8 + j][n = lane&15].
__global__ __launch_bounds__(256) void pack_kernel(
    const float* __restrict__ w1, const float* __restrict__ w2,
    unsigned short* __restrict__ w1p, unsigned short* __restrict__ w2p) {
  int e = blockIdx.x * 256 + threadIdx.x;
  if (e < 3 * 17 * 64 * 8) {
    int j = e & 7, lane = (e >> 3) & 63, fi = e >> 9;
    int kt = fi / 17, nt = fi - kt * 17;
    int k = kt * 32 + (lane >> 4) * 8 + j;
    int n = nt * 16 + (lane & 15);
    float v = (k < CIN_ && n < HID_) ? w1[k * HID_ + n] : 0.f;
    w1p[e] = f2bf(v);
  } else {
    int e2 = e - 3 * 17 * 64 * 8;
    if (e2 < 9 * 8 * 64 * 8) {
      int j = e2 & 7, lane = (e2 >> 3) & 63, fi = e2 >> 9;
      int kt = fi >> 3, nt = fi & 7;
      int k = kt * 32 + (lane >> 4) * 8 + j;
      int n = nt * 16 + (lane & 15);
      float v = (k < HID_) ? w2[k * OUT_ + n] : 0.f;
      w2p[e2] = f2bf(v);
    }
  }
}

// ---------------- Fused gather + MLP + LN + max, one center at a time -----
__global__ __launch_bounds__(512) void mlp_kernel(
    const float* __restrict__ x, const float* __restrict__ features,
    const float* __restrict__ centers, const int* __restrict__ nbr,
    const unsigned short* __restrict__ w1p, const float* __restrict__ b1,
    const float* __restrict__ g1, const float* __restrict__ be1,
    const unsigned short* __restrict__ w2p, const float* __restrict__ b2,
    const float* __restrict__ g2, const float* __restrict__ be2,
    float* __restrict__ out1) {
  __shared__ __align__(16) unsigned short A1[32 * 104];  // comb bf16, K1pad=96 (+8 pad)
  __shared__ __align__(16) unsigned short H1[32 * 296];  // h1 bf16, K2pad=288 (+8 pad)
  __shared__ float H2[32 * 132];                          // h2 f32 (pre-LN2), +4 pad
  __shared__ float s_sum[32], s_sum2[32], s_mu[32], s_rs[32];
  __shared__ int s_nbr[32];
  __shared__ float s_ctr[3];

  const int tid = threadIdx.x;
  const int lane = tid & 63;
  const int wv = tid >> 6;   // wave 0..7
  const int q4 = lane >> 4;  // quad 0..3
  const int nl = lane & 15;

  for (int e = tid; e < 32 * 104; e += 512) A1[e] = 0;
  for (int e = tid; e < 32 * 296; e += 512) H1[e] = 0;
  __syncthreads();

  for (int cm = blockIdx.x; cm < B_ * M_; cm += gridDim.x) {
    const int b = cm >> 11;
    if (tid < 32) s_nbr[tid] = nbr[(size_t)cm * K_ + tid];
    else if (tid < 64) s_sum[tid - 32] = 0.f;
    else if (tid < 96) s_sum2[tid - 64] = 0.f;
    else if (tid < 99) s_ctr[tid - 96] = centers[(size_t)cm * 3 + (tid - 96)];
    __syncthreads();

    // gather: 16 threads per neighbor row
    {
      int r = tid >> 4, j = tid & 15;
      int idx = s_nbr[r];
      const float4* frow = (const float4*)(features + ((size_t)b * N_ + idx) * C_);
      float4 f4 = frow[j];
      int base = r * 104 + j * 4;
      A1[base + 0] = f2bf(f4.x); A1[base + 1] = f2bf(f4.y);
      A1[base + 2] = f2bf(f4.z); A1[base + 3] = f2bf(f4.w);
      if (j == 0) {
        const float* xp = x + ((size_t)b * N_ + idx) * 3;
        A1[r * 104 + 64] = f2bf(xp[0] - s_ctr[0]);
        A1[r * 104 + 65] = f2bf(xp[1] - s_ctr[1]);
        A1[r * 104 + 66] = f2bf(xp[2] - s_ctr[2]);
      }
    }
    __syncthreads();

    // GEMM1: (32x96) @ (96x272), B-frags register-cached from global
    for (int nt = wv; nt < 17; nt += 8) {
      short8 bfr[3];
#pragma unroll
      for (int kt = 0; kt < 3; ++kt)
        bfr[kt] = *(const short8*)(w1p + (size_t)((kt * 17 + nt) * 64 + lane) * 8);
      int col = nt * 16 + nl;
      bool cok = col < HID_;
      float bias = cok ? b1[col] : 0.f;
#pragma unroll
      for (int mt = 0; mt < 2; ++mt) {
        floatx4 acc = {0.f, 0.f, 0.f, 0.f};
        const unsigned short* ap = A1 + (mt * 16 + nl) * 104 + q4 * 8;
#pragma unroll
        for (int kt = 0; kt < 3; ++kt) {
          short8 a = *(const short8*)(ap + kt * 32);
          acc = __builtin_amdgcn_mfma_f32_16x16x32_bf16(a, bfr[kt], acc, 0, 0, 0);
        }
#pragma unroll
        for (int r = 0; r < 4; ++r) {
          int row = mt * 16 + q4 * 4 + r;
          float g = 0.f;
          if (cok) {
            float v = acc[r] + bias;
            g = gelu_tanh(v);
            H1[row * 296 + col] = f2bf(g);
          }
          float s1 = g, s2 = g * g;
#pragma unroll
          for (int off = 1; off < 16; off <<= 1) {
            s1 += __shfl_xor(s1, off);
            s2 += __shfl_xor(s2, off);
          }
          if (nl == 0) { atomicAdd(&s_sum[row], s1); atomicAdd(&s_sum2[row], s2); }
        }
      }
    }
    __syncthreads();
    if (tid < 32) {
      float mu = s_sum[tid] * (1.f / HID_);
      float var = s_sum2[tid] * (1.f / HID_) - mu * mu;
      s_mu[tid] = mu;
      s_rs[tid] = rsqrtf(var + EPS_);
    }
    __syncthreads();
    // LN1 in place (bf16), zero stats for LN2
    for (int e = tid; e < K_ * HID_; e += 512) {
      int r = e / HID_, c = e - r * HID_;
      float g = bf2f(H1[r * 296 + c]);
      float v = (g - s_mu[r]) * s_rs[r] * g1[c] + be1[c];
      H1[r * 296 + c] = f2bf(v);
    }
    if (tid < 32) { s_sum[tid] = 0.f; s_sum2[tid] = 0.f; }
    __syncthreads();

    // GEMM2: (32x288) @ (288x128), one n-tile per wave
    {
      int nt = wv;
      short8 bfr2[9];
#pragma unroll
      for (int kt = 0; kt < 9; ++kt)
        bfr2[kt] = *(const short8*)(w2p + (size_t)((kt * 8 + nt) * 64 + lane) * 8);
      int col = nt * 16 + nl;
      float bias = b2[col];
#pragma unroll
      for (int mt = 0; mt < 2; ++mt) {
        floatx4 acc = {0.f, 0.f, 0.f, 0.f};
        const unsigned short* ap = H1 + (mt * 16 + nl) * 296 + q4 * 8;
#pragma unroll
        for (int kt = 0; kt < 9; ++kt) {
          short8 a = *(const short8*)(ap + kt * 32);
          acc = __builtin_amdgcn_mfma_f32_16x16x32_bf16(a, bfr2[kt], acc, 0, 0, 0);
        }
#pragma unroll
        for (int r = 0; r < 4; ++r) {
          int row = mt * 16 + q4 * 4 + r;
          float v = acc[r] + bias;
          H2[row * 132 + col] = v;
          float s1 = v, s2 = v * v;
#pragma unroll
          for (int off = 1; off < 16; off <<= 1) {
            s1 += __shfl_xor(s1, off);
            s2 += __shfl_xor(s2, off);
          }
          if (nl == 0) { atomicAdd(&s_sum[row], s1); atomicAdd(&s_sum2[row], s2); }
        }
      }
    }
    __syncthreads();
    if (tid < 32) {
      float mu = s_sum[tid] * (1.f / OUT_);
      float var = s_sum2[tid] * (1.f / OUT_) - mu * mu;
      s_mu[tid] = mu;
      s_rs[tid] = rsqrtf(var + EPS_);
    }
    __syncthreads();
    if (tid < OUT_) {
      int col = tid;
      float gg = g2[col], bb = be2[col];
      float mx = -3.4e38f;
#pragma unroll 4
      for (int r = 0; r < K_; ++r) {
        float v = H2[r * 132 + col];
        float o = (v - s_mu[r]) * s_rs[r] * gg + bb;
        mx = fmaxf(mx, o);
      }
      out1[(size_t)cm * OUT_ + col] = mx;   // FLOAT32 output
    }
    __syncthreads();
  }
}

extern "C" void kernel_launch(void* const* d_in, const int* in_sizes, int n_in,
                              void* d_out, int out_size, void* d_ws, size_t ws_size,
                              hipStream_t stream) {
  const float* x = (const float*)d_in[0];
  const float* features = (const float*)d_in[1];
  const int* first_idx = (const int*)d_in[2];
  const float* w1 = (const float*)d_in[3];
  const float* b1 = (const float*)d_in[4];
  const float* g1 = (const float*)d_in[5];
  const float* be1 = (const float*)d_in[6];
  const float* w2 = (const float*)d_in[7];
  const float* b2 = (const float*)d_in[8];
  const float* g2 = (const float*)d_in[9];
  const float* be2 = (const float*)d_in[10];

  // d_out is FLOAT32: centers (8,2048,3) then out (8,2048,128), concatenated.
  float* centers = (float*)d_out;
  float* out1 = (float*)d_out + (size_t)B_ * M_ * 3;

  // ws layout (bytes): nbr [0,2097152) | w1p [2097152,2149376) | w2p [2149376,2223104)
  int* nbr = (int*)d_ws;
  unsigned short* w1p = (unsigned short*)((char*)d_ws + 2097152);
  unsigned short* w2p = (unsigned short*)((char*)d_ws + 2149376);

  pack_kernel<<<dim3(246), dim3(256), 0, stream>>>(w1, w2, w1p, w2p);
  fps_kernel<<<dim3(B_), dim3(512), 0, stream>>>(x, first_idx, centers);
  ballq_kernel<<<dim3((B_ * M_) / 4), dim3(256), 0, stream>>>(x, centers, nbr);
  mlp_kernel<<<dim3(512), dim3(512), 0, stream>>>(x, features, centers, nbr,
                                                  w1p, b1, g1, be1, w2p, b2, g2, be2, out1);
}

// Round 15
// 3125.634 us; speedup vs baseline: 1.5120x; 1.0464x over previous
//
#include <hip/hip_runtime.h>
#include <hip/hip_bf16.h>
#include <math.h>

#define B_ 8
#define N_ 8192
#define C_ 64
#define M_ 2048
#define K_ 32
#define OUT_ 128
#define CIN_ 67
#define HID_ 268
#define EPS_ 1e-6f

typedef short short8 __attribute__((ext_vector_type(8)));
typedef float floatx4 __attribute__((ext_vector_type(4)));

__device__ __forceinline__ unsigned short f2bf(float f) {
  unsigned u = __builtin_bit_cast(unsigned, f);
  u += 0x7fffu + ((u >> 16) & 1u);   // RNE (MFMA input casts only)
  return (unsigned short)(u >> 16);
}
__device__ __forceinline__ float bf2f(unsigned short h) {
  return __builtin_bit_cast(float, (unsigned)h << 16);
}

// Reference-matching distance (verified r13, bit-exact): square fused into the
// 3-element reduce as FMA, index-ascending.
__device__ __forceinline__ float d2fma(float ax, float ay, float az,
                                       float bx, float by, float bz) {
#pragma clang fp contract(off)
  float dx = ax - bx, dy = ay - by, dz = az - bz;
  return __builtin_fmaf(dz, dz, __builtin_fmaf(dy, dy, dx * dx));
}

__device__ __forceinline__ float gelu_tanh(float v) {
  const float k0 = 0.7978845608028654f;  // sqrt(2/pi)
  const float k1 = 0.044715f;
  float u = k0 * (v + k1 * v * v * v);
  return 0.5f * v * (1.0f + tanhf(u));
}

// ---------------- FPS v3: one block per batch, 512 threads ----------------
// x staged in LDS (96 KB) -> winner-coord fetch is an LDS broadcast, not a
// VMEM round-trip. Per-point u64 keys (bits(d)<<32 | ~idx) + register tree
// max (4 levels) + 6-step wave shuffle + parity-buffered cross-wave partials
// (1 barrier/iter). Selection chain bit-identical to the r13-verified one:
// same d2fma, same fminf, strict-max with first-global-index tie-break.
__global__ __launch_bounds__(512) void fps_kernel(
    const float* __restrict__ x, const int* __restrict__ first_idx,
    float* __restrict__ centers) {   // = d_out[0 .. B*M*3), FLOAT32
  const int b = blockIdx.x;
  const int t = threadIdx.x;
  const int lane = t & 63;
  const int wv = t >> 6;
  const float* xb = x + (size_t)b * N_ * 3;

  __shared__ float s_xyz[N_ * 3];                 // 96 KB coord cache
  __shared__ unsigned long long s_part[2][8];

  // stage coords: 24576 floats = 6144 float4, coalesced, 12 per thread
  {
    const float4* src = (const float4*)xb;
    float4* dst = (float4*)s_xyz;
#pragma unroll
    for (int i = 0; i < 12; ++i) {
      int e = t + i * 512;
      dst[e] = src[e];
    }
  }
  __syncthreads();

  float px[16], py[16], pz[16], d[16];
  unsigned lo[16];   // precomputed ~idx per slot (tie-break: bigger = smaller idx)
#pragma unroll
  for (int i = 0; i < 16; ++i) {
    int p = t + i * 512;
    px[i] = s_xyz[p * 3 + 0];
    py[i] = s_xyz[p * 3 + 1];
    pz[i] = s_xyz[p * 3 + 2];
    d[i] = INFINITY;   // fminf(inf, v) == v exactly -> first update installs d0
    lo[i] = 0xFFFFFFFFu - (unsigned)p;
  }

  int fi = first_idx[b];
  float ncx = s_xyz[fi * 3 + 0], ncy = s_xyz[fi * 3 + 1], ncz = s_xyz[fi * 3 + 2];
  if (t == 0) {
    size_t co = (size_t)b * M_ * 3;
    centers[co + 0] = ncx; centers[co + 1] = ncy; centers[co + 2] = ncz;
  }

  for (int it = 1; it < M_; ++it) {
    // fused: min-update with center[it-1] + per-point key build
    unsigned long long k[16];
#pragma unroll
    for (int i = 0; i < 16; ++i) {
      float dd = d2fma(px[i], py[i], pz[i], ncx, ncy, ncz);
      float dm = fminf(d[i], dd);
      d[i] = dm;
      k[i] = ((unsigned long long)__builtin_bit_cast(unsigned, dm) << 32) |
             (unsigned long long)lo[i];
    }
    // register tree max over 16 keys (4 dependent levels, not 16)
#pragma unroll
    for (int s = 8; s >= 1; s >>= 1)
#pragma unroll
      for (int i = 0; i < s; ++i)
        k[i] = k[i] > k[i + s] ? k[i] : k[i + s];
    unsigned long long kk = k[0];
    // wave reduce (64 lanes)
#pragma unroll
    for (int off = 1; off < 64; off <<= 1) {
      unsigned long long o = __shfl_xor(kk, off);
      kk = kk > o ? kk : o;
    }
    if (lane == 0) s_part[it & 1][wv] = kk;
    __syncthreads();
    // tree over the 8 per-wave partials (broadcast LDS reads)
    {
      const unsigned long long* sp = s_part[it & 1];
      unsigned long long a0 = sp[0] > sp[1] ? sp[0] : sp[1];
      unsigned long long a1 = sp[2] > sp[3] ? sp[2] : sp[3];
      unsigned long long a2 = sp[4] > sp[5] ? sp[4] : sp[5];
      unsigned long long a3 = sp[6] > sp[7] ? sp[6] : sp[7];
      unsigned long long b0 = a0 > a1 ? a0 : a1;
      unsigned long long b1 = a2 > a3 ? a2 : a3;
      kk = b0 > b1 ? b0 : b1;
    }
    int gi = (int)(0xFFFFFFFFu - (unsigned)(kk & 0xFFFFFFFFull));
    int gs = __builtin_amdgcn_readfirstlane(gi);   // uniform index
    ncx = s_xyz[gs * 3 + 0];                        // LDS broadcast fetch
    ncy = s_xyz[gs * 3 + 1];
    ncz = s_xyz[gs * 3 + 2];
    if (t == 0) {
      size_t co = ((size_t)b * M_ + it) * 3;
      centers[co + 0] = ncx; centers[co + 1] = ncy; centers[co + 2] = ncz;
    }
    // no second barrier: next iteration writes the other parity buffer
  }
}

// ---------------- Ball query: one wave per center -------------------------
#define CAP_ 512
__global__ __launch_bounds__(256) void ballq_kernel(
    const float* __restrict__ x, const float* __restrict__ centers,
    int* __restrict__ nbr) {
  __shared__ float cd[4][CAP_];
  __shared__ int cidx[4][CAP_];
  const int w = threadIdx.x >> 6;
  const int lane = threadIdx.x & 63;
  const int cm = blockIdx.x * 4 + w;
  const int b = cm >> 11;  // / M_
  const float* xb = x + (size_t)b * N_ * 3;
  const float ccx = centers[(size_t)cm * 3 + 0];
  const float ccy = centers[(size_t)cm * 3 + 1];
  const float ccz = centers[(size_t)cm * 3 + 2];
  int count = 0;
  for (int base = 0; base < N_; base += 64) {
    int p = base + lane;
    float d2 = d2fma(xb[p * 3 + 0], xb[p * 3 + 1], xb[p * 3 + 2], ccx, ccy, ccz);
    bool isin = d2 < 0.09f;   // f32(0.3**2), strict <
    unsigned long long m = __ballot(isin);
    if (isin) {
      int pos = count + (int)__popcll(m & ((1ull << lane) - 1ull));
      if (pos < CAP_) { cd[w][pos] = d2; cidx[w][pos] = p; }  // index-ordered = stable
    }
    count += (int)__popcll(m);
  }
  if (count > CAP_) count = CAP_;
  int nw = count < K_ ? count : K_;
  for (int cc = lane; cc < count; cc += 64) {
    float dcc = cd[w][cc];
    int rank = 0;
    for (int j = 0; j < count; ++j) {
      float dj = cd[w][j];
      rank += (dj < dcc || (dj == dcc && j < cc)) ? 1 : 0;  // stable order
    }
    if (rank < K_) nbr[(size_t)cm * K_ + rank] = cidx[w][cc];
  }
  // pad: reference's -1 wraps to N-1 on gather
  for (int s = nw + lane; s < K_; s += 64) nbr[(size_t)cm * K_ + s] = N_ - 1;
}

// ---------------- Pack f32 weights into MFMA B-fragment order (bf16) ------
// B-frag for 16x16x32: lane holds B[k = (lane>>4)*8 + j][n = lane&15].
__global__ __launch_bounds__(256) void pack_kernel(
    const float* __restrict__ w1, const float* __restrict__ w2,
    unsigned short* __restrict__ w1p, unsigned short* __restrict__ w2p) {
  int e = blockIdx.x * 256 + threadIdx.x;
  if (e < 3 * 17 * 64 * 8) {
    int j = e & 7, lane = (e >> 3) & 63, fi = e >> 9;
    int kt = fi / 17, nt = fi - kt * 17;
    int k = kt * 32 + (lane >> 4) * 8 + j;
    int n = nt * 16 + (lane & 15);
    float v = (k < CIN_ && n < HID_) ? w1[k * HID_ + n] : 0.f;
    w1p[e] = f2bf(v);
  } else {
    int e2 = e - 3 * 17 * 64 * 8;
    if (e2 < 9 * 8 * 64 * 8) {
      int j = e2 & 7, lane = (e2 >> 3) & 63, fi = e2 >> 9;
      int kt = fi >> 3, nt = fi & 7;
      int k = kt * 32 + (lane >> 4) * 8 + j;
      int n = nt * 16 + (lane & 15);
      float v = (k < HID_) ? w2[k * OUT_ + n] : 0.f;
      w2p[e2] = f2bf(v);
    }
  }
}

// ---------------- Fused gather + MLP + LN + max, one center at a time -----
__global__ __launch_bounds__(512) void mlp_kernel(
    const float* __restrict__ x, const float* __restrict__ features,
    const float* __restrict__ centers, const int* __restrict__ nbr,
    const unsigned short* __restrict__ w1p, const float* __restrict__ b1,
    const float* __restrict__ g1, const float* __restrict__ be1,
    const unsigned short* __restrict__ w2p, const float* __restrict__ b2,
    const float* __restrict__ g2, const float* __restrict__ be2,
    float* __restrict__ out1) {
  __shared__ __align__(16) unsigned short A1[32 * 104];  // comb bf16, K1pad=96 (+8 pad)
  __shared__ __align__(16) unsigned short H1[32 * 296];  // h1 bf16, K2pad=288 (+8 pad)
  __shared__ float H2[32 * 132];                          // h2 f32 (pre-LN2), +4 pad
  __shared__ float s_sum[32], s_sum2[32], s_mu[32], s_rs[32];
  __shared__ int s_nbr[32];
  __shared__ float s_ctr[3];

  const int tid = threadIdx.x;
  const int lane = tid & 63;
  const int wv = tid >> 6;   // wave 0..7
  const int q4 = lane >> 4;  // quad 0..3
  const int nl = lane & 15;

  for (int e = tid; e < 32 * 104; e += 512) A1[e] = 0;
  for (int e = tid; e < 32 * 296; e += 512) H1[e] = 0;
  __syncthreads();

  for (int cm = blockIdx.x; cm < B_ * M_; cm += gridDim.x) {
    const int b = cm >> 11;
    if (tid < 32) s_nbr[tid] = nbr[(size_t)cm * K_ + tid];
    else if (tid < 64) s_sum[tid - 32] = 0.f;
    else if (tid < 96) s_sum2[tid - 64] = 0.f;
    else if (tid < 99) s_ctr[tid - 96] = centers[(size_t)cm * 3 + (tid - 96)];
    __syncthreads();

    // gather: 16 threads per neighbor row
    {
      int r = tid >> 4, j = tid & 15;
      int idx = s_nbr[r];
      const float4* frow = (const float4*)(features + ((size_t)b * N_ + idx) * C_);
      float4 f4 = frow[j];
      int base = r * 104 + j * 4;
      A1[base + 0] = f2bf(f4.x); A1[base + 1] = f2bf(f4.y);
      A1[base + 2] = f2bf(f4.z); A1[base + 3] = f2bf(f4.w);
      if (j == 0) {
        const float* xp = x + ((size_t)b * N_ + idx) * 3;
        A1[r * 104 + 64] = f2bf(xp[0] - s_ctr[0]);
        A1[r * 104 + 65] = f2bf(xp[1] - s_ctr[1]);
        A1[r * 104 + 66] = f2bf(xp[2] - s_ctr[2]);
      }
    }
    __syncthreads();

    // GEMM1: (32x96) @ (96x272), B-frags register-cached from global
    for (int nt = wv; nt < 17; nt += 8) {
      short8 bfr[3];
#pragma unroll
      for (int kt = 0; kt < 3; ++kt)
        bfr[kt] = *(const short8*)(w1p + (size_t)((kt * 17 + nt) * 64 + lane) * 8);
      int col = nt * 16 + nl;
      bool cok = col < HID_;
      float bias = cok ? b1[col] : 0.f;
#pragma unroll
      for (int mt = 0; mt < 2; ++mt) {
        floatx4 acc = {0.f, 0.f, 0.f, 0.f};
        const unsigned short* ap = A1 + (mt * 16 + nl) * 104 + q4 * 8;
#pragma unroll
        for (int kt = 0; kt < 3; ++kt) {
          short8 a = *(const short8*)(ap + kt * 32);
          acc = __builtin_amdgcn_mfma_f32_16x16x32_bf16(a, bfr[kt], acc, 0, 0, 0);
        }
#pragma unroll
        for (int r = 0; r < 4; ++r) {
          int row = mt * 16 + q4 * 4 + r;
          float g = 0.f;
          if (cok) {
            float v = acc[r] + bias;
            g = gelu_tanh(v);
            H1[row * 296 + col] = f2bf(g);
          }
          float s1 = g, s2 = g * g;
#pragma unroll
          for (int off = 1; off < 16; off <<= 1) {
            s1 += __shfl_xor(s1, off);
            s2 += __shfl_xor(s2, off);
          }
          if (nl == 0) { atomicAdd(&s_sum[row], s1); atomicAdd(&s_sum2[row], s2); }
        }
      }
    }
    __syncthreads();
    if (tid < 32) {
      float mu = s_sum[tid] * (1.f / HID_);
      float var = s_sum2[tid] * (1.f / HID_) - mu * mu;
      s_mu[tid] = mu;
      s_rs[tid] = rsqrtf(var + EPS_);
    }
    __syncthreads();
    // LN1 in place (bf16), zero stats for LN2
    for (int e = tid; e < K_ * HID_; e += 512) {
      int r = e / HID_, c = e - r * HID_;
      float g = bf2f(H1[r * 296 + c]);
      float v = (g - s_mu[r]) * s_rs[r] * g1[c] + be1[c];
      H1[r * 296 + c] = f2bf(v);
    }
    if (tid < 32) { s_sum[tid] = 0.f; s_sum2[tid] = 0.f; }
    __syncthreads();

    // GEMM2: (32x288) @ (288x128), one n-tile per wave
    {
      int nt = wv;
      short8 bfr2[9];
#pragma unroll
      for (int kt = 0; kt < 9; ++kt)
        bfr2[kt] = *(const short8*)(w2p + (size_t)((kt * 8 + nt) * 64 + lane) * 8);
      int col = nt * 16 + nl;
      float bias = b2[col];
#pragma unroll
      for (int mt = 0; mt < 2; ++mt) {
        floatx4 acc = {0.f, 0.f, 0.f, 0.f};
        const unsigned short* ap = H1 + (mt * 16 + nl) * 296 + q4 * 8;
#pragma unroll
        for (int kt = 0; kt < 9; ++kt) {
          short8 a = *(const short8*)(ap + kt * 32);
          acc = __builtin_amdgcn_mfma_f32_16x16x32_bf16(a, bfr2[kt], acc, 0, 0, 0);
        }
#pragma unroll
        for (int r = 0; r < 4; ++r) {
          int row = mt * 16 + q4 * 4 + r;
          float v = acc[r] + bias;
          H2[row * 132 + col] = v;
          float s1 = v, s2 = v * v;
#pragma unroll
          for (int off = 1; off < 16; off <<= 1) {
            s1 += __shfl_xor(s1, off);
            s2 += __shfl_xor(s2, off);
          }
          if (nl == 0) { atomicAdd(&s_sum[row], s1); atomicAdd(&s_sum2[row], s2); }
        }
      }
    }
    __syncthreads();
    if (tid < 32) {
      float mu = s_sum[tid] * (1.f / OUT_);
      float var = s_sum2[tid] * (1.f / OUT_) - mu * mu;
      s_mu[tid] = mu;
      s_rs[tid] = rsqrtf(var + EPS_);
    }
    __syncthreads();
    if (tid < OUT_) {
      int col = tid;
      float gg = g2[col], bb = be2[col];
      float mx = -3.4e38f;
#pragma unroll 4
      for (int r = 0; r < K_; ++r) {
        float v = H2[r * 132 + col];
        float o = (v - s_mu[r]) * s_rs[r] * gg + bb;
        mx = fmaxf(mx, o);
      }
      out1[(size_t)cm * OUT_ + col] = mx;   // FLOAT32 output
    }
    __syncthreads();
  }
}

extern "C" void kernel_launch(void* const* d_in, const int* in_sizes, int n_in,
                              void* d_out, int out_size, void* d_ws, size_t ws_size,
                              hipStream_t stream) {
  const float* x = (const float*)d_in[0];
  const float* features = (const float*)d_in[1];
  const int* first_idx = (const int*)d_in[2];
  const float* w1 = (const float*)d_in[3];
  const float* b1 = (const float*)d_in[4];
  const float* g1 = (const float*)d_in[5];
  const float* be1 = (const float*)d_in[6];
  const float* w2 = (const float*)d_in[7];
  const float* b2 = (const float*)d_in[8];
  const float* g2 = (const float*)d_in[9];
  const float* be2 = (const float*)d_in[10];

  // d_out is FLOAT32: centers (8,2048,3) then out (8,2048,128), concatenated.
  float* centers = (float*)d_out;
  float* out1 = (float*)d_out + (size_t)B_ * M_ * 3;

  // ws layout (bytes): nbr [0,2097152) | w1p [2097152,2149376) | w2p [2149376,2223104)
  int* nbr = (int*)d_ws;
  unsigned short* w1p = (unsigned short*)((char*)d_ws + 2097152);
  unsigned short* w2p = (unsigned short*)((char*)d_ws + 2149376);

  pack_kernel<<<dim3(246), dim3(256), 0, stream>>>(w1, w2, w1p, w2p);
  fps_kernel<<<dim3(B_), dim3(512), 0, stream>>>(x, first_idx, centers);
  ballq_kernel<<<dim3((B_ * M_) / 4), dim3(256), 0, stream>>>(x, centers, nbr);
  mlp_kernel<<<dim3(512), dim3(512), 0, stream>>>(x, features, centers, nbr,
                                                  w1p, b1, g1, be1, w2p, b2, g2, be2, out1);
}